// Round 1
// baseline (360.086 us; speedup 1.0000x reference)
//
#include <hip/hip_runtime.h>
#include <stdint.h>

typedef unsigned short u16;
typedef __bf16 bf16_t;
typedef bf16_t v8bf __attribute__((ext_vector_type(8)));
typedef float v4f __attribute__((ext_vector_type(4)));

#define SEQ   4096
#define HIDN  1024
#define NHEAD 16
#define HDIM  64
#define BLK   256
#define NBLK  16

__device__ __forceinline__ u16 f2bf(float f){
  union { float f; unsigned u; } v; v.f = f;
  unsigned r = (v.u + 0x7fffu + ((v.u >> 16) & 1u)) >> 16;   // RNE
  return (u16)r;
}
__device__ __forceinline__ float bf2f(u16 h){
  union { unsigned u; float f; } v; v.u = ((unsigned)h) << 16;
  return v.f;
}

// ---------------- elementwise f32 -> bf16 ----------------
__global__ void k_f32_to_bf16(const float* __restrict__ in, u16* __restrict__ out, int n){
  int i = (blockIdx.x * blockDim.x + threadIdx.x) * 4;
  if (i + 3 < n){
    float4 f = *(const float4*)&in[i];
    unsigned u0 = (unsigned)f2bf(f.x) | ((unsigned)f2bf(f.y) << 16);
    unsigned u1 = (unsigned)f2bf(f.z) | ((unsigned)f2bf(f.w) << 16);
    uint2 p; p.x = u0; p.y = u1;
    *(uint2*)&out[i] = p;
  }
}

// ---------------- 1024x1024 transpose, f32 -> bf16 (Wt[n][k] = W[k][n]) ----------------
__global__ void k_transpose_bf16(const float* __restrict__ in, u16* __restrict__ out){
  __shared__ float t[32][33];
  int x = threadIdx.x & 31, y = threadIdx.x >> 5;      // 32 x 8
  int k0 = blockIdx.x * 32, n0 = blockIdx.y * 32;
  #pragma unroll
  for (int yy = 0; yy < 32; yy += 8) t[y + yy][x] = in[(size_t)(k0 + y + yy) * 1024 + n0 + x];
  __syncthreads();
  #pragma unroll
  for (int yy = 0; yy < 32; yy += 8) out[(size_t)(n0 + y + yy) * 1024 + k0 + x] = f2bf(t[x][y + yy]);
}

// ---------------- bf16 MFMA GEMM: C[M,N] = A[M,K] * Wt[N,K]^T + bias ----------------
// 128x128 tile, BK=32, 4 waves (2x2), each wave 64x64 via 4x4 16x16x32 MFMAs.
__global__ __launch_bounds__(256) void k_gemm(const u16* __restrict__ A, const u16* __restrict__ Bt,
                                              const float* __restrict__ bias, void* __restrict__ Cout,
                                              int M, int N, int K, int out_f32)
{
  __shared__ alignas(16) u16 As[128 * 40];
  __shared__ alignas(16) u16 Bs[128 * 40];
  int tid = threadIdx.x, lane = tid & 63, wid = tid >> 6;
  int wr = wid >> 1, wc = wid & 1;
  int m0 = blockIdx.y * 128, n0 = blockIdx.x * 128;

  v4f acc[4][4];
  #pragma unroll
  for (int m = 0; m < 4; m++)
    #pragma unroll
    for (int n = 0; n < 4; n++) acc[m][n] = (v4f){0.f, 0.f, 0.f, 0.f};

  int r = lane & 15, g = lane >> 4;

  for (int kt = 0; kt < K; kt += 32){
    #pragma unroll
    for (int it = 0; it < 2; ++it){
      int id = it * 256 + tid;
      int row = id >> 2, seg = id & 3;
      *(uint4*)&As[row * 40 + seg * 8] = *(const uint4*)&A[(size_t)(m0 + row) * K + kt + seg * 8];
      *(uint4*)&Bs[row * 40 + seg * 8] = *(const uint4*)&Bt[(size_t)(n0 + row) * K + kt + seg * 8];
    }
    __syncthreads();
    v8bf a[4], b[4];
    #pragma unroll
    for (int m = 0; m < 4; m++) a[m] = *(const v8bf*)&As[(wr * 64 + m * 16 + r) * 40 + g * 8];
    #pragma unroll
    for (int n = 0; n < 4; n++) b[n] = *(const v8bf*)&Bs[(wc * 64 + n * 16 + r) * 40 + g * 8];
    #pragma unroll
    for (int m = 0; m < 4; m++)
      #pragma unroll
      for (int n = 0; n < 4; n++)
        acc[m][n] = __builtin_amdgcn_mfma_f32_16x16x32_bf16(a[m], b[n], acc[m][n], 0, 0, 0);
    __syncthreads();
  }

  #pragma unroll
  for (int m = 0; m < 4; m++)
    #pragma unroll
    for (int n = 0; n < 4; n++){
      int col = n0 + wc * 64 + n * 16 + r;
      float bv = bias[col];
      #pragma unroll
      for (int i = 0; i < 4; i++){
        int row = m0 + wr * 64 + m * 16 + g * 4 + i;
        float val = acc[m][n][i] + bv;
        if (out_f32) ((float*)Cout)[(size_t)row * N + col] = val;
        else         ((u16*)Cout)[(size_t)row * N + col] = f2bf(val);
      }
    }
}

// ---------------- position projections (f32, head 0 only) ----------------
// blocks 0..255: posk[b][d] = rpe[b] . Wk[:,d] + bk[d]   (d<64)
// block 256:     posq0[d]   = rpe[0] . Wq[:,d] + bq[d]
__global__ void k_pos_proj(const float* __restrict__ rpe,
                           const float* __restrict__ Wq, const float* __restrict__ bq,
                           const float* __restrict__ Wk, const float* __restrict__ bk,
                           float* __restrict__ posk, float* __restrict__ posq0)
{
  int b = blockIdx.x, d = threadIdx.x;
  if (b < 256){
    float s = 0.f;
    for (int k = 0; k < 1024; k++) s += rpe[(size_t)b * 1024 + k] * Wk[(size_t)k * 1024 + d];
    posk[b * 64 + d] = s + bk[d];
  } else {
    float s = 0.f;
    for (int k = 0; k < 1024; k++) s += rpe[k] * Wq[(size_t)k * 1024 + d];
    posq0[d] = s + bq[d];
  }
}

// ---------------- bias_row[t], t in [0,512): flat-take rows of c2p + p2c ----------------
__global__ void k_bias_row(const u16* __restrict__ qb, const u16* __restrict__ kb,
                           const float* __restrict__ posk, const float* __restrict__ posq0,
                           float* __restrict__ bias_row)
{
  int t = blockIdx.x * blockDim.x + threadIdx.x;   // 512
  float v = 0.f;
  if (t >= 256){
    int u = t - 256;
    float c2p = 0.f, p2c = 0.f;
    for (int d = 0; d < 64; d++){
      c2p += bf2f(qb[d]) * posk[u * 64 + d];                   // q row0 head0
      p2c += posq0[d] * bf2f(kb[(size_t)u * HIDN + d]);        // k row u head0
    }
    v = c2p + p2c;
  }
  bias_row[t] = v;
}

// ---------------- bias2[i][j] = bias_row[idx(i,j)], faithful log-bucket ----------------
__global__ void k_bias2(const float* __restrict__ bias_row, float* __restrict__ bias2)
{
  int gid = blockIdx.x * blockDim.x + threadIdx.x;   // 256*768
  int i = gid / 768, j = gid - i * 768;
  int rel = i - j;
  int bucket;
  bool in_exact = (rel < 128) && (rel > -128);
  int abs_pos = in_exact ? 127 : (rel < 0 ? -rel : rel);
  if (abs_pos <= 128) bucket = rel;
  else {
    float xx = logf((float)abs_pos * (1.0f / 128.0f)) / logf(255.0f / 128.0f);
    float lp = ceilf(xx * 127.0f) + 128.0f;
    int sgn = (rel > 0) ? 1 : ((rel < 0) ? -1 : 0);
    bucket = (int)lp * sgn;
  }
  int idx = bucket + 256;
  idx = idx < 0 ? 0 : (idx > 511 ? 511 : idx);
  bias2[gid] = bias_row[idx];
}

// ---------------- fused local attention per (block n, head h, q-tile of 64) ----------------
__global__ __launch_bounds__(256) void k_attn(const u16* __restrict__ qg, const u16* __restrict__ kg,
                                              const u16* __restrict__ vg, const float* __restrict__ bias2,
                                              u16* __restrict__ ctxg)
{
  __shared__ alignas(16) u16 Qs[64 * 72];
  __shared__ alignas(16) u16 KVs[128 * 72];          // K chunk [128][72] / Vt chunk [64][136]
  __shared__ alignas(16) u16 Ss[64 * 776];           // exp-scores, bf16
  __shared__ float invsum[64];

  int b = blockIdx.x;
  int n = b >> 6, h = (b >> 2) & 15, qt = b & 3;
  int tid = threadIdx.x, lane = tid & 63, wid = tid >> 6;
  int q0 = n * 256 + qt * 64;       // global first q row
  int qb0 = qt * 64;                // q row within block (bias2 row)
  int g0 = (n - 1) * 256;           // global row of key 0 of the 768-window
  const float inv_scale = 0.07216878364870323f;  // 1/sqrt(192)

  { // stage Q [64][64]
    int row = tid >> 2, seg = tid & 3;
    const u16* src = &qg[(size_t)(q0 + row) * HIDN + h * 64 + seg * 16];
    *(uint4*)&Qs[row * 72 + seg * 16]     = *(const uint4*)&src[0];
    *(uint4*)&Qs[row * 72 + seg * 16 + 8] = *(const uint4*)&src[8];
  }
  __syncthreads();

  int r = lane & 15, g = lane >> 4;

  // ---- phase 1: scores -> Ss (bf16 raw scores) ----
  for (int c = 0; c < 6; ++c){
    #pragma unroll
    for (int it = 0; it < 2; ++it){   // stage K chunk [128][64], zero-pad OOB
      int row = it * 64 + (tid >> 2), seg = tid & 3;
      int grow = g0 + c * 128 + row;
      uint4 d0, d1;
      d0.x = d0.y = d0.z = d0.w = 0; d1 = d0;
      if (grow >= 0 && grow < SEQ){
        const u16* src = &kg[(size_t)grow * HIDN + h * 64 + seg * 16];
        d0 = *(const uint4*)&src[0]; d1 = *(const uint4*)&src[8];
      }
      *(uint4*)&KVs[row * 72 + seg * 16]     = d0;
      *(uint4*)&KVs[row * 72 + seg * 16 + 8] = d1;
    }
    __syncthreads();
    v4f sacc[4][2];
    #pragma unroll
    for (int m = 0; m < 4; m++){ sacc[m][0] = (v4f){0.f,0.f,0.f,0.f}; sacc[m][1] = (v4f){0.f,0.f,0.f,0.f}; }
    #pragma unroll
    for (int ks = 0; ks < 2; ++ks){
      v8bf a[4], bb[2];
      #pragma unroll
      for (int m = 0; m < 4; m++) a[m] = *(const v8bf*)&Qs[(m * 16 + r) * 72 + ks * 32 + g * 8];
      #pragma unroll
      for (int nn = 0; nn < 2; nn++) bb[nn] = *(const v8bf*)&KVs[(wid * 32 + nn * 16 + r) * 72 + ks * 32 + g * 8];
      #pragma unroll
      for (int m = 0; m < 4; m++)
        #pragma unroll
        for (int nn = 0; nn < 2; nn++)
          sacc[m][nn] = __builtin_amdgcn_mfma_f32_16x16x32_bf16(a[m], bb[nn], sacc[m][nn], 0, 0, 0);
    }
    #pragma unroll
    for (int m = 0; m < 4; m++)
      #pragma unroll
      for (int nn = 0; nn < 2; nn++){
        int kcol = c * 128 + wid * 32 + nn * 16 + r;
        #pragma unroll
        for (int i = 0; i < 4; i++){
          int qrow = m * 16 + g * 4 + i;
          float sc = (sacc[m][nn][i] + bias2[(size_t)(qb0 + qrow) * 768 + kcol]) * inv_scale;
          Ss[qrow * 776 + kcol] = f2bf(sc);
        }
      }
    __syncthreads();
  }

  // ---- phase 2: softmax (store unnormalized exp, fold 1/sum into PV epilogue) ----
  {
    int row = tid >> 2, sub = tid & 3;
    float mx = -3.0e38f;
    for (int j = sub; j < 768; j += 4) mx = fmaxf(mx, bf2f(Ss[row * 776 + j]));
    mx = fmaxf(mx, __shfl_xor(mx, 1));
    mx = fmaxf(mx, __shfl_xor(mx, 2));
    float sm = 0.f;
    for (int j = sub; j < 768; j += 4){
      float e = expf(bf2f(Ss[row * 776 + j]) - mx);
      sm += e;
      Ss[row * 776 + j] = f2bf(e);
    }
    sm += __shfl_xor(sm, 1);
    sm += __shfl_xor(sm, 2);
    if (sub == 0) invsum[row] = 1.0f / sm;
  }
  __syncthreads();

  // ---- phase 3: PV ----
  v4f pacc[4];
  #pragma unroll
  for (int nn = 0; nn < 4; nn++) pacc[nn] = (v4f){0.f,0.f,0.f,0.f};
  for (int c = 0; c < 6; ++c){
    { // stage V chunk transposed: Vt[d][kk] = v[g0+c*128+kk][h*64+d]
      int kk = tid >> 1, half = tid & 1;
      int grow = g0 + c * 128 + kk;
      alignas(16) u16 tmp[32];
      if (grow >= 0 && grow < SEQ){
        const u16* src = &vg[(size_t)grow * HIDN + h * 64 + half * 32];
        *(uint4*)&tmp[0]  = *(const uint4*)&src[0];
        *(uint4*)&tmp[8]  = *(const uint4*)&src[8];
        *(uint4*)&tmp[16] = *(const uint4*)&src[16];
        *(uint4*)&tmp[24] = *(const uint4*)&src[24];
      } else {
        #pragma unroll
        for (int j = 0; j < 32; j++) tmp[j] = 0;
      }
      #pragma unroll
      for (int j = 0; j < 32; j++) KVs[(half * 32 + j) * 136 + kk] = tmp[j];
    }
    __syncthreads();
    #pragma unroll
    for (int ks = 0; ks < 4; ++ks){
      v8bf a = *(const v8bf*)&Ss[(wid * 16 + r) * 776 + c * 128 + ks * 32 + g * 8];
      #pragma unroll
      for (int nn = 0; nn < 4; nn++){
        v8bf bb = *(const v8bf*)&KVs[(nn * 16 + r) * 136 + ks * 32 + g * 8];
        pacc[nn] = __builtin_amdgcn_mfma_f32_16x16x32_bf16(a, bb, pacc[nn], 0, 0, 0);
      }
    }
    __syncthreads();
  }
  #pragma unroll
  for (int nn = 0; nn < 4; nn++){
    int d = nn * 16 + r;
    #pragma unroll
    for (int i = 0; i < 4; i++){
      int qrow = wid * 16 + g * 4 + i;
      float val = pacc[nn][i] * invsum[qrow];
      ctxg[(size_t)(q0 + qrow) * HIDN + h * 64 + d] = f2bf(val);
    }
  }
}

// ---------------- residual + LayerNorm (in place over d_out) ----------------
__global__ __launch_bounds__(256) void k_ln(const float* __restrict__ x, const float* __restrict__ resid,
                                            const float* __restrict__ gamma, const float* __restrict__ beta,
                                            float* __restrict__ out)
{
  __shared__ float red[8];
  int row = blockIdx.x, tid = threadIdx.x;
  int lane = tid & 63, wid = tid >> 6;
  size_t base = (size_t)row * 1024 + tid * 4;
  float4 xv = *(const float4*)&x[base];
  float4 rv = *(const float4*)&resid[base];
  float v0 = xv.x + rv.x, v1 = xv.y + rv.y, v2 = xv.z + rv.z, v3 = xv.w + rv.w;
  float s = v0 + v1 + v2 + v3;
  float q = v0 * v0 + v1 * v1 + v2 * v2 + v3 * v3;
  #pragma unroll
  for (int o = 32; o; o >>= 1){ s += __shfl_down(s, o); q += __shfl_down(q, o); }
  if (lane == 0){ red[wid] = s; red[4 + wid] = q; }
  __syncthreads();
  float ts = red[0] + red[1] + red[2] + red[3];
  float tq = red[4] + red[5] + red[6] + red[7];
  float mu = ts * (1.0f / 1024.0f);
  float var = tq * (1.0f / 1024.0f) - mu * mu;
  float rstd = rsqrtf(var + 1e-7f);
  int c = tid * 4;
  out[base + 0] = (v0 - mu) * rstd * gamma[c + 0] + beta[c + 0];
  out[base + 1] = (v1 - mu) * rstd * gamma[c + 1] + beta[c + 1];
  out[base + 2] = (v2 - mu) * rstd * gamma[c + 2] + beta[c + 2];
  out[base + 3] = (v3 - mu) * rstd * gamma[c + 3] + beta[c + 3];
}

extern "C" void kernel_launch(void* const* d_in, const int* in_sizes, int n_in,
                              void* d_out, int out_size, void* d_ws, size_t ws_size,
                              hipStream_t stream)
{
  const float* hidden = (const float*)d_in[0];
  const float* rpe    = (const float*)d_in[1];
  const float* Wq = (const float*)d_in[2];
  const float* bq = (const float*)d_in[3];
  const float* Wk = (const float*)d_in[4];
  const float* bk = (const float*)d_in[5];
  const float* Wv = (const float*)d_in[6];
  const float* bv = (const float*)d_in[7];
  const float* Wo = (const float*)d_in[8];
  const float* bo = (const float*)d_in[9];
  const float* lns = (const float*)d_in[10];
  const float* lnb = (const float*)d_in[11];
  float* out = (float*)d_out;

  char* ws = (char*)d_ws;
  size_t off = 0;
  auto alloc = [&](size_t bytes){ void* p = ws + off; off += (bytes + 255) & ~(size_t)255; return p; };
  u16* hb      = (u16*)alloc((size_t)SEQ * HIDN * 2);
  u16* Wqt     = (u16*)alloc((size_t)HIDN * HIDN * 2);
  u16* Wkt     = (u16*)alloc((size_t)HIDN * HIDN * 2);
  u16* Wvt     = (u16*)alloc((size_t)HIDN * HIDN * 2);
  u16* Wot     = (u16*)alloc((size_t)HIDN * HIDN * 2);
  u16* qb      = (u16*)alloc((size_t)SEQ * HIDN * 2);
  u16* kb      = (u16*)alloc((size_t)SEQ * HIDN * 2);
  u16* vb      = (u16*)alloc((size_t)SEQ * HIDN * 2);
  u16* ctxb    = (u16*)alloc((size_t)SEQ * HIDN * 2);
  float* poskf = (float*)alloc(256 * 64 * 4);
  float* posq0 = (float*)alloc(64 * 4);
  float* brow  = (float*)alloc(512 * 4);
  float* bias2 = (float*)alloc(256 * 768 * 4);
  (void)ws_size; (void)in_sizes; (void)n_in; (void)out_size;

  k_f32_to_bf16<<<SEQ * HIDN / 1024, 256, 0, stream>>>(hidden, hb, SEQ * HIDN);
  dim3 tg(32, 32);
  k_transpose_bf16<<<tg, 256, 0, stream>>>(Wq, Wqt);
  k_transpose_bf16<<<tg, 256, 0, stream>>>(Wk, Wkt);
  k_transpose_bf16<<<tg, 256, 0, stream>>>(Wv, Wvt);
  k_transpose_bf16<<<tg, 256, 0, stream>>>(Wo, Wot);

  dim3 gg(HIDN / 128, SEQ / 128);
  k_gemm<<<gg, 256, 0, stream>>>(hb, Wqt, bq, qb, SEQ, HIDN, HIDN, 0);
  k_gemm<<<gg, 256, 0, stream>>>(hb, Wkt, bk, kb, SEQ, HIDN, HIDN, 0);
  k_gemm<<<gg, 256, 0, stream>>>(hb, Wvt, bv, vb, SEQ, HIDN, HIDN, 0);

  k_pos_proj<<<257, 64, 0, stream>>>(rpe, Wq, bq, Wk, bk, poskf, posq0);
  k_bias_row<<<2, 256, 0, stream>>>(qb, kb, poskf, posq0, brow);
  k_bias2<<<768, 256, 0, stream>>>(brow, bias2);

  k_attn<<<NBLK * NHEAD * 4, 256, 0, stream>>>(qb, kb, vb, bias2, ctxb);

  k_gemm<<<gg, 256, 0, stream>>>(ctxb, Wot, bo, out, SEQ, HIDN, HIDN, 1);
  k_ln<<<SEQ, 256, 0, stream>>>(out, hidden, lns, lnb, out);
}

// Round 2
// 196.676 us; speedup vs baseline: 1.8309x; 1.8309x over previous
//
#include <hip/hip_runtime.h>
#include <stdint.h>

typedef unsigned short u16;
typedef __bf16 bf16_t;
typedef bf16_t v8bf __attribute__((ext_vector_type(8)));
typedef float v4f __attribute__((ext_vector_type(4)));

#define SEQ   4096
#define HIDN  1024
#define NHEAD 16
#define HDIM  64
#define BLK   256
#define NBLK  16

__device__ __forceinline__ u16 f2bf(float f){
  union { float f; unsigned u; } v; v.f = f;
  unsigned r = (v.u + 0x7fffu + ((v.u >> 16) & 1u)) >> 16;   // RNE
  return (u16)r;
}
__device__ __forceinline__ float bf2f(u16 h){
  union { unsigned u; float f; } v; v.u = ((unsigned)h) << 16;
  return v.f;
}

// ---------------- elementwise f32 -> bf16 ----------------
__global__ void k_f32_to_bf16(const float* __restrict__ in, u16* __restrict__ out, int n){
  int i = (blockIdx.x * blockDim.x + threadIdx.x) * 4;
  if (i + 3 < n){
    float4 f = *(const float4*)&in[i];
    unsigned u0 = (unsigned)f2bf(f.x) | ((unsigned)f2bf(f.y) << 16);
    unsigned u1 = (unsigned)f2bf(f.z) | ((unsigned)f2bf(f.w) << 16);
    uint2 p; p.x = u0; p.y = u1;
    *(uint2*)&out[i] = p;
  }
}

// ---------------- 1024x1024 transpose, f32 -> bf16 (Wt[n][k] = W[k][n]) ----------------
__global__ void k_transpose_bf16(const float* __restrict__ in, u16* __restrict__ out){
  __shared__ float t[32][33];
  int x = threadIdx.x & 31, y = threadIdx.x >> 5;      // 32 x 8
  int k0 = blockIdx.x * 32, n0 = blockIdx.y * 32;
  #pragma unroll
  for (int yy = 0; yy < 32; yy += 8) t[y + yy][x] = in[(size_t)(k0 + y + yy) * 1024 + n0 + x];
  __syncthreads();
  #pragma unroll
  for (int yy = 0; yy < 32; yy += 8) out[(size_t)(n0 + y + yy) * 1024 + k0 + x] = f2bf(t[x][y + yy]);
}

// ---------------- bf16 [4096][3072] -> Vt[c][s] transpose of the V slice ----------------
__global__ void k_vtrans(const u16* __restrict__ qkv, u16* __restrict__ Vt){
  __shared__ u16 t[32][33];
  int x = threadIdx.x & 31, y = threadIdx.x >> 5;
  int s0 = blockIdx.x * 32, c0 = blockIdx.y * 32;
  #pragma unroll
  for (int yy = 0; yy < 32; yy += 8) t[y + yy][x] = qkv[(size_t)(s0 + y + yy) * 3072 + 2048 + c0 + x];
  __syncthreads();
  #pragma unroll
  for (int yy = 0; yy < 32; yy += 8) Vt[(size_t)(c0 + y + yy) * 4096 + s0 + x] = t[x][y + yy];
}

// ---------------- bias concat [bq|bk|bv] ----------------
__global__ void k_bcat(const float* __restrict__ bq, const float* __restrict__ bk,
                       const float* __restrict__ bv, float* __restrict__ o){
  int i = blockIdx.x * 256 + threadIdx.x;   // 3072
  const float* src = i < 1024 ? bq : (i < 2048 ? bk : bv);
  o[i] = src[i & 1023];
}

// ---------------- bf16 MFMA GEMM: C[M,N] = A[M,K] * Wt[N,K]^T + bias ----------------
__global__ __launch_bounds__(256) void k_gemm(const u16* __restrict__ A, const u16* __restrict__ Bt,
                                              const float* __restrict__ bias, void* __restrict__ Cout,
                                              int M, int N, int K, int out_f32)
{
  __shared__ alignas(16) u16 As[128 * 40];
  __shared__ alignas(16) u16 Bs[128 * 40];
  int tid = threadIdx.x, lane = tid & 63, wid = tid >> 6;
  int wr = wid >> 1, wc = wid & 1;
  int m0 = blockIdx.y * 128, n0 = blockIdx.x * 128;

  v4f acc[4][4];
  #pragma unroll
  for (int m = 0; m < 4; m++)
    #pragma unroll
    for (int n = 0; n < 4; n++) acc[m][n] = (v4f){0.f, 0.f, 0.f, 0.f};

  int r = lane & 15, g = lane >> 4;

  for (int kt = 0; kt < K; kt += 32){
    #pragma unroll
    for (int it = 0; it < 2; ++it){
      int id = it * 256 + tid;
      int row = id >> 2, seg = id & 3;
      *(uint4*)&As[row * 40 + seg * 8] = *(const uint4*)&A[(size_t)(m0 + row) * K + kt + seg * 8];
      *(uint4*)&Bs[row * 40 + seg * 8] = *(const uint4*)&Bt[(size_t)(n0 + row) * K + kt + seg * 8];
    }
    __syncthreads();
    v8bf a[4], b[4];
    #pragma unroll
    for (int m = 0; m < 4; m++) a[m] = *(const v8bf*)&As[(wr * 64 + m * 16 + r) * 40 + g * 8];
    #pragma unroll
    for (int n = 0; n < 4; n++) b[n] = *(const v8bf*)&Bs[(wc * 64 + n * 16 + r) * 40 + g * 8];
    #pragma unroll
    for (int m = 0; m < 4; m++)
      #pragma unroll
      for (int n = 0; n < 4; n++)
        acc[m][n] = __builtin_amdgcn_mfma_f32_16x16x32_bf16(a[m], b[n], acc[m][n], 0, 0, 0);
    __syncthreads();
  }

  #pragma unroll
  for (int m = 0; m < 4; m++)
    #pragma unroll
    for (int n = 0; n < 4; n++){
      int col = n0 + wc * 64 + n * 16 + r;
      float bv = bias[col];
      #pragma unroll
      for (int i = 0; i < 4; i++){
        int row = m0 + wr * 64 + m * 16 + g * 4 + i;
        float val = acc[m][n][i] + bv;
        if (out_f32) ((float*)Cout)[(size_t)row * N + col] = val;
        else         ((u16*)Cout)[(size_t)row * N + col] = f2bf(val);
      }
    }
}

// ---------------- position projections (f32, head 0 only), 256 thr/block ----------------
__global__ __launch_bounds__(256) void k_pos_proj(const float* __restrict__ rpe,
                           const float* __restrict__ Wq, const float* __restrict__ bq,
                           const float* __restrict__ Wk, const float* __restrict__ bk,
                           float* __restrict__ posk, float* __restrict__ posq0)
{
  __shared__ float red[4][64];
  int b = blockIdx.x, t = threadIdx.x, d = t & 63, part = t >> 6;
  const float* W  = (b < 256) ? Wk : Wq;
  const float* rv = (b < 256) ? &rpe[(size_t)b * 1024] : rpe;
  float s = 0.f;
  for (int k = part * 256; k < part * 256 + 256; k++) s += rv[k] * W[(size_t)k * 1024 + d];
  red[part][d] = s;
  __syncthreads();
  if (part == 0){
    s = red[0][d] + red[1][d] + red[2][d] + red[3][d];
    if (b < 256) posk[b * 64 + d] = s + bk[d];
    else         posq0[d] = s + bq[d];
  }
}

// ---------------- bias_row[t], t in [0,512) ----------------
__global__ void k_bias_row(const u16* __restrict__ qkv,
                           const float* __restrict__ posk, const float* __restrict__ posq0,
                           float* __restrict__ bias_row)
{
  int t = blockIdx.x * blockDim.x + threadIdx.x;   // 512
  float v = 0.f;
  if (t >= 256){
    int u = t - 256;
    float c2p = 0.f, p2c = 0.f;
    for (int d = 0; d < 64; d++){
      c2p += bf2f(qkv[d]) * posk[u * 64 + d];                   // q row0 head0
      p2c += posq0[d] * bf2f(qkv[(size_t)u * 3072 + 1024 + d]); // k row u head0
    }
    v = c2p + p2c;
  }
  bias_row[t] = v;
}

// ---------------- bias2[i][j] = bias_row[idx(i,j)], faithful log-bucket ----------------
__global__ void k_bias2(const float* __restrict__ bias_row, float* __restrict__ bias2)
{
  int gid = blockIdx.x * blockDim.x + threadIdx.x;   // 256*768
  int i = gid / 768, j = gid - i * 768;
  int rel = i - j;
  int bucket;
  bool in_exact = (rel < 128) && (rel > -128);
  int abs_pos = in_exact ? 127 : (rel < 0 ? -rel : rel);
  if (abs_pos <= 128) bucket = rel;
  else {
    float xx = logf((float)abs_pos * (1.0f / 128.0f)) / logf(255.0f / 128.0f);
    float lp = ceilf(xx * 127.0f) + 128.0f;
    int sgn = (rel > 0) ? 1 : ((rel < 0) ? -1 : 0);
    bucket = (int)lp * sgn;
  }
  int idx = bucket + 256;
  idx = idx < 0 ? 0 : (idx > 511 ? 511 : idx);
  bias2[gid] = bias_row[idx];
}

// ---------------- fused local attention: WG = (n, h, qtile of 32 rows) ----------------
__global__ __launch_bounds__(256) void k_attn(const u16* __restrict__ qkv, const u16* __restrict__ Vt,
                                              const float* __restrict__ bias2, u16* __restrict__ ctxg)
{
  __shared__ alignas(16) u16 Qs[32 * 72];
  __shared__ alignas(16) u16 KVs[128 * 72];          // K chunk [128][72] / Vt chunk [64][136]
  __shared__ alignas(16) u16 Ss[32 * 776];           // scores then exp-scores, bf16
  __shared__ float invsum[32];

  int b = blockIdx.x;
  int qt = b & 7, h = (b >> 3) & 15, n = b >> 7;
  int tid = threadIdx.x, lane = tid & 63, wid = tid >> 6;
  int q0 = n * 256 + qt * 32;       // global first q row
  int qb0 = qt * 32;                // q row within block (bias2 row)
  int g0 = (n - 1) * 256;           // global row of key 0 of the 768-window
  const float inv_scale = 0.07216878364870323f;  // 1/sqrt(192)

  { // stage Q [32][64]
    int row = tid >> 3, seg = tid & 7;
    *(uint4*)&Qs[row * 72 + seg * 8] =
      *(const uint4*)&qkv[(size_t)(q0 + row) * 3072 + h * 64 + seg * 8];
  }
  __syncthreads();

  int r = lane & 15, g = lane >> 4;
  int qf = wid >> 1;                 // q fragment (16 rows) for QK and PV
  int kh = wid & 1;                  // k half (64 cols) in QK
  int dh = wid & 1;                  // d half (32 cols) in PV

  // ---- phase 1: scores -> Ss ----
  for (int c = 0; c < 6; ++c){
    int cb = g0 + c * 128;
    bool oob = (cb < 0) || (cb >= SEQ);
    if (!oob){
      #pragma unroll
      for (int it = 0; it < 2; ++it){   // stage K chunk [128][64]
        int row = it * 64 + (tid >> 2), seg = tid & 3;
        const u16* src = &qkv[(size_t)(cb + row) * 3072 + 1024 + h * 64 + seg * 16];
        *(uint4*)&KVs[row * 72 + seg * 16]     = *(const uint4*)&src[0];
        *(uint4*)&KVs[row * 72 + seg * 16 + 8] = *(const uint4*)&src[8];
      }
    }
    __syncthreads();
    v4f sacc[4];
    #pragma unroll
    for (int nn = 0; nn < 4; nn++) sacc[nn] = (v4f){0.f,0.f,0.f,0.f};
    if (!oob){
      #pragma unroll
      for (int ks = 0; ks < 2; ++ks){
        v8bf a = *(const v8bf*)&Qs[(qf * 16 + r) * 72 + ks * 32 + g * 8];
        #pragma unroll
        for (int nn = 0; nn < 4; nn++){
          v8bf bb = *(const v8bf*)&KVs[(kh * 64 + nn * 16 + r) * 72 + ks * 32 + g * 8];
          sacc[nn] = __builtin_amdgcn_mfma_f32_16x16x32_bf16(a, bb, sacc[nn], 0, 0, 0);
        }
      }
    }
    #pragma unroll
    for (int nn = 0; nn < 4; nn++){
      int kcol = c * 128 + kh * 64 + nn * 16 + r;
      #pragma unroll
      for (int i = 0; i < 4; i++){
        int qrow = qf * 16 + g * 4 + i;
        float sc = (sacc[nn][i] + bias2[(size_t)(qb0 + qrow) * 768 + kcol]) * inv_scale;
        Ss[qrow * 776 + kcol] = f2bf(sc);
      }
    }
    __syncthreads();
  }

  // ---- phase 2: vectorized softmax (8 threads / row, b128 ops) ----
  {
    int row = tid >> 3, sub = tid & 7;
    u16* srow = &Ss[row * 776 + sub * 96];
    float mx = -3.0e38f;
    #pragma unroll
    for (int ii = 0; ii < 12; ii++){
      uint4 pk = *(const uint4*)&srow[ii * 8];
      const unsigned* w = (const unsigned*)&pk;
      #pragma unroll
      for (int j = 0; j < 4; j++){
        mx = fmaxf(mx, bf2f((u16)(w[j] & 0xffff)));
        mx = fmaxf(mx, bf2f((u16)(w[j] >> 16)));
      }
    }
    mx = fmaxf(mx, __shfl_xor(mx, 1));
    mx = fmaxf(mx, __shfl_xor(mx, 2));
    mx = fmaxf(mx, __shfl_xor(mx, 4));
    float sm = 0.f;
    #pragma unroll
    for (int ii = 0; ii < 12; ii++){
      uint4 pk = *(const uint4*)&srow[ii * 8];
      unsigned* w = (unsigned*)&pk;
      #pragma unroll
      for (int j = 0; j < 4; j++){
        float e0 = __expf(bf2f((u16)(w[j] & 0xffff)) - mx);
        float e1 = __expf(bf2f((u16)(w[j] >> 16)) - mx);
        sm += e0 + e1;
        w[j] = (unsigned)f2bf(e0) | ((unsigned)f2bf(e1) << 16);
      }
      *(uint4*)&srow[ii * 8] = pk;
    }
    sm += __shfl_xor(sm, 1);
    sm += __shfl_xor(sm, 2);
    sm += __shfl_xor(sm, 4);
    if (sub == 0) invsum[row] = 1.0f / sm;
  }
  __syncthreads();

  // ---- phase 3: PV ----
  v4f pacc[2];
  pacc[0] = (v4f){0.f,0.f,0.f,0.f};
  pacc[1] = (v4f){0.f,0.f,0.f,0.f};
  for (int c = 0; c < 6; ++c){
    int cb = g0 + c * 128;
    bool oob = (cb < 0) || (cb >= SEQ);
    if (!oob){
      int d = tid >> 2, seg = tid & 3;
      const u16* src = &Vt[(size_t)(h * 64 + d) * 4096 + cb];
      #pragma unroll
      for (int ii = 0; ii < 4; ii++)
        *(uint4*)&KVs[d * 136 + (ii * 4 + seg) * 8] = *(const uint4*)&src[(ii * 4 + seg) * 8];
    }
    __syncthreads();
    if (!oob){
      #pragma unroll
      for (int ks = 0; ks < 4; ++ks){
        v8bf a = *(const v8bf*)&Ss[(qf * 16 + r) * 776 + c * 128 + ks * 32 + g * 8];
        #pragma unroll
        for (int nn = 0; nn < 2; nn++){
          v8bf bb = *(const v8bf*)&KVs[(dh * 32 + nn * 16 + r) * 136 + ks * 32 + g * 8];
          pacc[nn] = __builtin_amdgcn_mfma_f32_16x16x32_bf16(a, bb, pacc[nn], 0, 0, 0);
        }
      }
    }
    __syncthreads();
  }
  #pragma unroll
  for (int nn = 0; nn < 2; nn++){
    int d = dh * 32 + nn * 16 + r;
    #pragma unroll
    for (int i = 0; i < 4; i++){
      int qrow = qf * 16 + g * 4 + i;
      float val = pacc[nn][i] * invsum[qrow];
      ctxg[(size_t)(q0 + qrow) * 1024 + h * 64 + d] = f2bf(val);
    }
  }
}

// ---------------- residual + LayerNorm (in place over d_out) ----------------
__global__ __launch_bounds__(256) void k_ln(const float* __restrict__ x, const float* __restrict__ resid,
                                            const float* __restrict__ gamma, const float* __restrict__ beta,
                                            float* __restrict__ out)
{
  __shared__ float red[8];
  int row = blockIdx.x, tid = threadIdx.x;
  int lane = tid & 63, wid = tid >> 6;
  size_t base = (size_t)row * 1024 + tid * 4;
  float4 xv = *(const float4*)&x[base];
  float4 rv = *(const float4*)&resid[base];
  float v0 = xv.x + rv.x, v1 = xv.y + rv.y, v2 = xv.z + rv.z, v3 = xv.w + rv.w;
  float s = v0 + v1 + v2 + v3;
  float q = v0 * v0 + v1 * v1 + v2 * v2 + v3 * v3;
  #pragma unroll
  for (int o = 32; o; o >>= 1){ s += __shfl_down(s, o); q += __shfl_down(q, o); }
  if (lane == 0){ red[wid] = s; red[4 + wid] = q; }
  __syncthreads();
  float ts = red[0] + red[1] + red[2] + red[3];
  float tq = red[4] + red[5] + red[6] + red[7];
  float mu = ts * (1.0f / 1024.0f);
  float var = tq * (1.0f / 1024.0f) - mu * mu;
  float rstd = rsqrtf(var + 1e-7f);
  int c = tid * 4;
  out[base + 0] = (v0 - mu) * rstd * gamma[c + 0] + beta[c + 0];
  out[base + 1] = (v1 - mu) * rstd * gamma[c + 1] + beta[c + 1];
  out[base + 2] = (v2 - mu) * rstd * gamma[c + 2] + beta[c + 2];
  out[base + 3] = (v3 - mu) * rstd * gamma[c + 3] + beta[c + 3];
}

extern "C" void kernel_launch(void* const* d_in, const int* in_sizes, int n_in,
                              void* d_out, int out_size, void* d_ws, size_t ws_size,
                              hipStream_t stream)
{
  const float* hidden = (const float*)d_in[0];
  const float* rpe    = (const float*)d_in[1];
  const float* Wq = (const float*)d_in[2];
  const float* bq = (const float*)d_in[3];
  const float* Wk = (const float*)d_in[4];
  const float* bk = (const float*)d_in[5];
  const float* Wv = (const float*)d_in[6];
  const float* bv = (const float*)d_in[7];
  const float* Wo = (const float*)d_in[8];
  const float* bo = (const float*)d_in[9];
  const float* lns = (const float*)d_in[10];
  const float* lnb = (const float*)d_in[11];
  float* out = (float*)d_out;

  char* ws = (char*)d_ws;
  size_t off = 0;
  auto alloc = [&](size_t bytes){ void* p = ws + off; off += (bytes + 255) & ~(size_t)255; return p; };
  u16* hb      = (u16*)alloc((size_t)SEQ * HIDN * 2);         // aliased as Vt after QKV GEMM
  u16* Wt      = (u16*)alloc((size_t)3 * HIDN * HIDN * 2);    // [Wqt|Wkt|Wvt] rows
  u16* Wot     = (u16*)alloc((size_t)HIDN * HIDN * 2);
  u16* qkv     = (u16*)alloc((size_t)SEQ * 3 * HIDN * 2);
  u16* ctxb    = (u16*)alloc((size_t)SEQ * HIDN * 2);
  float* bcat  = (float*)alloc(3072 * 4);
  float* poskf = (float*)alloc(256 * 64 * 4);
  float* posq0 = (float*)alloc(64 * 4);
  float* brow  = (float*)alloc(512 * 4);
  float* bias2 = (float*)alloc(256 * 768 * 4);
  u16* Vt = hb;
  (void)ws_size; (void)in_sizes; (void)n_in; (void)out_size;

  k_f32_to_bf16<<<SEQ * HIDN / 1024, 256, 0, stream>>>(hidden, hb, SEQ * HIDN);
  dim3 tg(32, 32);
  k_transpose_bf16<<<tg, 256, 0, stream>>>(Wq, Wt);
  k_transpose_bf16<<<tg, 256, 0, stream>>>(Wk, Wt + (size_t)HIDN * HIDN);
  k_transpose_bf16<<<tg, 256, 0, stream>>>(Wv, Wt + (size_t)2 * HIDN * HIDN);
  k_transpose_bf16<<<tg, 256, 0, stream>>>(Wo, Wot);
  k_bcat<<<12, 256, 0, stream>>>(bq, bk, bv, bcat);

  dim3 gq(3 * HIDN / 128, SEQ / 128);
  k_gemm<<<gq, 256, 0, stream>>>(hb, Wt, bcat, qkv, SEQ, 3 * HIDN, HIDN, 0);

  k_vtrans<<<dim3(SEQ / 32, HIDN / 32), 256, 0, stream>>>(qkv, Vt);

  k_pos_proj<<<257, 256, 0, stream>>>(rpe, Wq, bq, Wk, bk, poskf, posq0);
  k_bias_row<<<2, 256, 0, stream>>>(qkv, poskf, posq0, brow);
  k_bias2<<<768, 256, 0, stream>>>(brow, bias2);

  k_attn<<<NBLK * NHEAD * 8, 256, 0, stream>>>(qkv, Vt, bias2, ctxb);

  dim3 go(HIDN / 128, SEQ / 128);
  k_gemm<<<go, 256, 0, stream>>>(ctxb, Wot, bo, out, SEQ, HIDN, HIDN, 1);
  k_ln<<<SEQ, 256, 0, stream>>>(out, hidden, lns, lnb, out);
}

// Round 3
// 192.662 us; speedup vs baseline: 1.8690x; 1.0208x over previous
//
#include <hip/hip_runtime.h>
#include <stdint.h>

typedef unsigned short u16;
typedef __bf16 bf16_t;
typedef bf16_t v8bf __attribute__((ext_vector_type(8)));
typedef float v4f __attribute__((ext_vector_type(4)));

#define SEQ   4096
#define HIDN  1024
#define NHEAD 16
#define HDIM  64
#define BLK   256
#define NBLK  16

#define GLOAD_LDS16(g, l) __builtin_amdgcn_global_load_lds( \
  (const __attribute__((address_space(1))) unsigned*)(g), \
  (__attribute__((address_space(3))) unsigned*)(l), 16, 0, 0)

__device__ __forceinline__ u16 f2bf(float f){
  union { float f; unsigned u; } v; v.f = f;
  unsigned r = (v.u + 0x7fffu + ((v.u >> 16) & 1u)) >> 16;   // RNE
  return (u16)r;
}
__device__ __forceinline__ float bf2f(u16 h){
  union { unsigned u; float f; } v; v.u = ((unsigned)h) << 16;
  return v.f;
}

// ---------------- elementwise f32 -> bf16 ----------------
__global__ void k_f32_to_bf16(const float* __restrict__ in, u16* __restrict__ out, int n){
  int i = (blockIdx.x * blockDim.x + threadIdx.x) * 4;
  if (i + 3 < n){
    float4 f = *(const float4*)&in[i];
    unsigned u0 = (unsigned)f2bf(f.x) | ((unsigned)f2bf(f.y) << 16);
    unsigned u1 = (unsigned)f2bf(f.z) | ((unsigned)f2bf(f.w) << 16);
    uint2 p; p.x = u0; p.y = u1;
    *(uint2*)&out[i] = p;
  }
}

// ---------------- 1024x1024 transpose, f32 -> bf16 (Wt[n][k] = W[k][n]) ----------------
__global__ void k_transpose_bf16(const float* __restrict__ in, u16* __restrict__ out){
  __shared__ float t[32][33];
  int x = threadIdx.x & 31, y = threadIdx.x >> 5;      // 32 x 8
  int k0 = blockIdx.x * 32, n0 = blockIdx.y * 32;
  #pragma unroll
  for (int yy = 0; yy < 32; yy += 8) t[y + yy][x] = in[(size_t)(k0 + y + yy) * 1024 + n0 + x];
  __syncthreads();
  #pragma unroll
  for (int yy = 0; yy < 32; yy += 8) out[(size_t)(n0 + y + yy) * 1024 + k0 + x] = f2bf(t[x][y + yy]);
}

// ---------------- bf16 [4096][3072] -> Vt[c][s] transpose of the V slice ----------------
__global__ void k_vtrans(const u16* __restrict__ qkv, u16* __restrict__ Vt){
  __shared__ u16 t[32][33];
  int x = threadIdx.x & 31, y = threadIdx.x >> 5;
  int s0 = blockIdx.x * 32, c0 = blockIdx.y * 32;
  #pragma unroll
  for (int yy = 0; yy < 32; yy += 8) t[y + yy][x] = qkv[(size_t)(s0 + y + yy) * 3072 + 2048 + c0 + x];
  __syncthreads();
  #pragma unroll
  for (int yy = 0; yy < 32; yy += 8) Vt[(size_t)(c0 + y + yy) * 4096 + s0 + x] = t[x][y + yy];
}

// ---------------- bias concat [bq|bk|bv] ----------------
__global__ void k_bcat(const float* __restrict__ bq, const float* __restrict__ bk,
                       const float* __restrict__ bv, float* __restrict__ o){
  int i = blockIdx.x * 256 + threadIdx.x;   // 3072
  const float* src = i < 1024 ? bq : (i < 2048 ? bk : bv);
  o[i] = src[i & 1023];
}

// ---------------- bf16 MFMA GEMM (m97 structure): C = A[M,K] * Bt[N,K]^T + bias ----------------
// 128x128 tile, BK=32, linear LDS [128][32]u16, global_load_lds 16B staging.
__global__ __launch_bounds__(256) void k_gemm(const u16* __restrict__ A, const u16* __restrict__ Bt,
                                              const float* __restrict__ bias, void* __restrict__ Cout,
                                              int M, int N, int K, int out_f32)
{
  __shared__ alignas(16) u16 As[128 * 32];
  __shared__ alignas(16) u16 Bs[128 * 32];
  int tid = threadIdx.x, lane = tid & 63, wid = tid >> 6;
  int wr = wid >> 1, wc = wid & 1;
  int m0 = blockIdx.y * 128, n0 = blockIdx.x * 128;

  v4f acc[4][4];
  #pragma unroll
  for (int m = 0; m < 4; m++)
    #pragma unroll
    for (int n = 0; n < 4; n++) acc[m][n] = (v4f){0.f, 0.f, 0.f, 0.f};

  int r = lane & 15, g = lane >> 4;
  // per-lane staging coords: byte o = ob + lane*16 in the 8KB buffer; row = o/64, col = (o%64)/2
  int ob0 = wid * 2048;

  for (int kt = 0; kt < K; kt += 32){
    #pragma unroll
    for (int t = 0; t < 2; ++t){
      int ob = ob0 + t * 1024;            // wave-uniform LDS byte base
      int o  = ob + lane * 16;            // this lane's slot
      int row = o >> 6, col = (o & 63) >> 1;
      GLOAD_LDS16(&A [(size_t)(m0 + row) * K + kt + col], As + (ob >> 1));
      GLOAD_LDS16(&Bt[(size_t)(n0 + row) * K + kt + col], Bs + (ob >> 1));
    }
    __syncthreads();
    v8bf a[4], b[4];
    #pragma unroll
    for (int m = 0; m < 4; m++) a[m] = *(const v8bf*)&As[(wr * 64 + m * 16 + r) * 32 + g * 8];
    #pragma unroll
    for (int n = 0; n < 4; n++) b[n] = *(const v8bf*)&Bs[(wc * 64 + n * 16 + r) * 32 + g * 8];
    #pragma unroll
    for (int m = 0; m < 4; m++)
      #pragma unroll
      for (int n = 0; n < 4; n++)
        acc[m][n] = __builtin_amdgcn_mfma_f32_16x16x32_bf16(a[m], b[n], acc[m][n], 0, 0, 0);
    __syncthreads();
  }

  #pragma unroll
  for (int m = 0; m < 4; m++)
    #pragma unroll
    for (int n = 0; n < 4; n++){
      int col = n0 + wc * 64 + n * 16 + r;
      float bv = bias[col];
      #pragma unroll
      for (int i = 0; i < 4; i++){
        int row = m0 + wr * 64 + m * 16 + g * 4 + i;
        float val = acc[m][n][i] + bv;
        if (out_f32) ((float*)Cout)[(size_t)row * N + col] = val;
        else         ((u16*)Cout)[(size_t)row * N + col] = f2bf(val);
      }
    }
}

// ---------------- position projections (f32, head 0 only), 256 thr/block ----------------
__global__ __launch_bounds__(256) void k_pos_proj(const float* __restrict__ rpe,
                           const float* __restrict__ Wq, const float* __restrict__ bq,
                           const float* __restrict__ Wk, const float* __restrict__ bk,
                           float* __restrict__ posk, float* __restrict__ posq0)
{
  __shared__ float red[4][64];
  int b = blockIdx.x, t = threadIdx.x, d = t & 63, part = t >> 6;
  const float* W  = (b < 256) ? Wk : Wq;
  const float* rv = (b < 256) ? &rpe[(size_t)b * 1024] : rpe;
  float s = 0.f;
  for (int k = part * 256; k < part * 256 + 256; k++) s += rv[k] * W[(size_t)k * 1024 + d];
  red[part][d] = s;
  __syncthreads();
  if (part == 0){
    s = red[0][d] + red[1][d] + red[2][d] + red[3][d];
    if (b < 256) posk[b * 64 + d] = s + bk[d];
    else         posq0[d] = s + bq[d];
  }
}

// ---------------- bias_row[t], t in [0,512) ----------------
__global__ void k_bias_row(const u16* __restrict__ qkv,
                           const float* __restrict__ posk, const float* __restrict__ posq0,
                           float* __restrict__ bias_row)
{
  int t = blockIdx.x * blockDim.x + threadIdx.x;   // 512
  float v = 0.f;
  if (t >= 256){
    int u = t - 256;
    float c2p = 0.f, p2c = 0.f;
    for (int d = 0; d < 64; d++){
      c2p += bf2f(qkv[d]) * posk[u * 64 + d];                   // q row0 head0
      p2c += posq0[d] * bf2f(qkv[(size_t)u * 3072 + 1024 + d]); // k row u head0
    }
    v = c2p + p2c;
  }
  bias_row[t] = v;
}

// ---------------- biasd[t] = brow[clip(bucket(t-767)+256)], t in [0,1024) ----------------
__global__ void k_biasd(const float* __restrict__ brow, float* __restrict__ biasd)
{
  int t = blockIdx.x * blockDim.x + threadIdx.x;   // 1024
  int rel = t - 767;
  int bucket;
  bool in_exact = (rel < 128) && (rel > -128);
  int abs_pos = in_exact ? 127 : (rel < 0 ? -rel : rel);
  if (abs_pos <= 128) bucket = rel;
  else {
    float xx = logf((float)abs_pos * (1.0f / 128.0f)) / logf(255.0f / 128.0f);
    float lp = ceilf(xx * 127.0f) + 128.0f;
    int sgn = (rel > 0) ? 1 : ((rel < 0) ? -1 : 0);
    bucket = (int)lp * sgn;
  }
  int idx = bucket + 256;
  idx = idx < 0 ? 0 : (idx > 511 ? 511 : idx);
  biasd[t] = brow[idx];
}

// ---------------- fused local attention: WG = (n, h, qtile of 32 rows) ----------------
__global__ __launch_bounds__(256) void k_attn(const u16* __restrict__ qkv, const u16* __restrict__ Vt,
                                              const float* __restrict__ biasd, u16* __restrict__ ctxg)
{
  __shared__ alignas(16) u16 Qs[32 * 72];
  __shared__ alignas(16) u16 KVs[128 * 72];          // K chunk [128][72] / Vt chunk [64][136]
  __shared__ alignas(16) u16 Ss[32 * 776];           // scores then exp-scores, bf16
  __shared__ float invsum[32];
  __shared__ float bias_s[1024];

  int b = blockIdx.x;
  int qt = b & 7, h = (b >> 3) & 15, n = b >> 7;
  int tid = threadIdx.x, lane = tid & 63, wid = tid >> 6;
  int q0 = n * 256 + qt * 32;       // global first q row
  int qb0 = qt * 32;                // q row within block (bias row base)
  int g0 = (n - 1) * 256;           // global row of key 0 of the 768-window
  const float inv_scale = 0.07216878364870323f;  // 1/sqrt(192)

  { // stage Q [32][64] + bias table
    int row = tid >> 3, seg = tid & 7;
    *(uint4*)&Qs[row * 72 + seg * 8] =
      *(const uint4*)&qkv[(size_t)(q0 + row) * 3072 + h * 64 + seg * 8];
    *(float4*)&bias_s[tid * 4] = *(const float4*)&biasd[tid * 4];
  }
  __syncthreads();

  int r = lane & 15, g = lane >> 4;
  int qf = wid >> 1;                 // q fragment (16 rows) for QK and PV
  int kh = wid & 1;                  // k half (64 cols) in QK
  int dh = wid & 1;                  // d half (32 cols) in PV

  // ---- phase 1: scores -> Ss ----
  for (int c = 0; c < 6; ++c){
    int cb = g0 + c * 128;
    bool oob = (cb < 0) || (cb >= SEQ);
    if (!oob){
      #pragma unroll
      for (int it = 0; it < 2; ++it){   // stage K chunk [128][64]
        int row = it * 64 + (tid >> 2), seg = tid & 3;
        const u16* src = &qkv[(size_t)(cb + row) * 3072 + 1024 + h * 64 + seg * 16];
        *(uint4*)&KVs[row * 72 + seg * 16]     = *(const uint4*)&src[0];
        *(uint4*)&KVs[row * 72 + seg * 16 + 8] = *(const uint4*)&src[8];
      }
    }
    __syncthreads();
    v4f sacc[4];
    #pragma unroll
    for (int nn = 0; nn < 4; nn++) sacc[nn] = (v4f){0.f,0.f,0.f,0.f};
    if (!oob){
      #pragma unroll
      for (int ks = 0; ks < 2; ++ks){
        v8bf a = *(const v8bf*)&Qs[(qf * 16 + r) * 72 + ks * 32 + g * 8];
        #pragma unroll
        for (int nn = 0; nn < 4; nn++){
          v8bf bb = *(const v8bf*)&KVs[(kh * 64 + nn * 16 + r) * 72 + ks * 32 + g * 8];
          sacc[nn] = __builtin_amdgcn_mfma_f32_16x16x32_bf16(a, bb, sacc[nn], 0, 0, 0);
        }
      }
    }
    #pragma unroll
    for (int nn = 0; nn < 4; nn++){
      int kcol = c * 128 + kh * 64 + nn * 16 + r;
      #pragma unroll
      for (int i = 0; i < 4; i++){
        int qrow = qf * 16 + g * 4 + i;
        float sc = (sacc[nn][i] + bias_s[qb0 + qrow - kcol + 767]) * inv_scale;
        Ss[qrow * 776 + kcol] = f2bf(sc);
      }
    }
    __syncthreads();
  }

  // ---- phase 2: vectorized softmax (8 threads / row, b128 ops) ----
  {
    int row = tid >> 3, sub = tid & 7;
    u16* srow = &Ss[row * 776 + sub * 96];
    float mx = -3.0e38f;
    #pragma unroll
    for (int ii = 0; ii < 12; ii++){
      uint4 pk = *(const uint4*)&srow[ii * 8];
      const unsigned* w = (const unsigned*)&pk;
      #pragma unroll
      for (int j = 0; j < 4; j++){
        mx = fmaxf(mx, bf2f((u16)(w[j] & 0xffff)));
        mx = fmaxf(mx, bf2f((u16)(w[j] >> 16)));
      }
    }
    mx = fmaxf(mx, __shfl_xor(mx, 1));
    mx = fmaxf(mx, __shfl_xor(mx, 2));
    mx = fmaxf(mx, __shfl_xor(mx, 4));
    float sm = 0.f;
    #pragma unroll
    for (int ii = 0; ii < 12; ii++){
      uint4 pk = *(const uint4*)&srow[ii * 8];
      unsigned* w = (unsigned*)&pk;
      #pragma unroll
      for (int j = 0; j < 4; j++){
        float e0 = __expf(bf2f((u16)(w[j] & 0xffff)) - mx);
        float e1 = __expf(bf2f((u16)(w[j] >> 16)) - mx);
        sm += e0 + e1;
        w[j] = (unsigned)f2bf(e0) | ((unsigned)f2bf(e1) << 16);
      }
      *(uint4*)&srow[ii * 8] = pk;
    }
    sm += __shfl_xor(sm, 1);
    sm += __shfl_xor(sm, 2);
    sm += __shfl_xor(sm, 4);
    if (sub == 0) invsum[row] = 1.0f / sm;
  }
  __syncthreads();

  // ---- phase 3: PV ----
  v4f pacc[2];
  pacc[0] = (v4f){0.f,0.f,0.f,0.f};
  pacc[1] = (v4f){0.f,0.f,0.f,0.f};
  for (int c = 0; c < 6; ++c){
    int cb = g0 + c * 128;
    bool oob = (cb < 0) || (cb >= SEQ);
    if (!oob){
      int d = tid >> 2, seg = tid & 3;
      const u16* src = &Vt[(size_t)(h * 64 + d) * 4096 + cb];
      #pragma unroll
      for (int ii = 0; ii < 4; ii++)
        *(uint4*)&KVs[d * 136 + (ii * 4 + seg) * 8] = *(const uint4*)&src[(ii * 4 + seg) * 8];
    }
    __syncthreads();
    if (!oob){
      #pragma unroll
      for (int ks = 0; ks < 4; ++ks){
        v8bf a = *(const v8bf*)&Ss[(qf * 16 + r) * 776 + c * 128 + ks * 32 + g * 8];
        #pragma unroll
        for (int nn = 0; nn < 2; nn++){
          v8bf bb = *(const v8bf*)&KVs[(dh * 32 + nn * 16 + r) * 136 + ks * 32 + g * 8];
          pacc[nn] = __builtin_amdgcn_mfma_f32_16x16x32_bf16(a, bb, pacc[nn], 0, 0, 0);
        }
      }
    }
    __syncthreads();
  }
  #pragma unroll
  for (int nn = 0; nn < 2; nn++){
    int d = dh * 32 + nn * 16 + r;
    #pragma unroll
    for (int i = 0; i < 4; i++){
      int qrow = qf * 16 + g * 4 + i;
      float val = pacc[nn][i] * invsum[qrow];
      ctxg[(size_t)(q0 + qrow) * 1024 + h * 64 + d] = f2bf(val);
    }
  }
}

// ---------------- residual + LayerNorm (in place over d_out) ----------------
__global__ __launch_bounds__(256) void k_ln(const float* __restrict__ x, const float* __restrict__ resid,
                                            const float* __restrict__ gamma, const float* __restrict__ beta,
                                            float* __restrict__ out)
{
  __shared__ float red[8];
  int row = blockIdx.x, tid = threadIdx.x;
  int lane = tid & 63, wid = tid >> 6;
  size_t base = (size_t)row * 1024 + tid * 4;
  float4 xv = *(const float4*)&x[base];
  float4 rv = *(const float4*)&resid[base];
  float v0 = xv.x + rv.x, v1 = xv.y + rv.y, v2 = xv.z + rv.z, v3 = xv.w + rv.w;
  float s = v0 + v1 + v2 + v3;
  float q = v0 * v0 + v1 * v1 + v2 * v2 + v3 * v3;
  #pragma unroll
  for (int o = 32; o; o >>= 1){ s += __shfl_down(s, o); q += __shfl_down(q, o); }
  if (lane == 0){ red[wid] = s; red[4 + wid] = q; }
  __syncthreads();
  float ts = red[0] + red[1] + red[2] + red[3];
  float tq = red[4] + red[5] + red[6] + red[7];
  float mu = ts * (1.0f / 1024.0f);
  float var = tq * (1.0f / 1024.0f) - mu * mu;
  float rstd = rsqrtf(var + 1e-7f);
  int c = tid * 4;
  out[base + 0] = (v0 - mu) * rstd * gamma[c + 0] + beta[c + 0];
  out[base + 1] = (v1 - mu) * rstd * gamma[c + 1] + beta[c + 1];
  out[base + 2] = (v2 - mu) * rstd * gamma[c + 2] + beta[c + 2];
  out[base + 3] = (v3 - mu) * rstd * gamma[c + 3] + beta[c + 3];
}

extern "C" void kernel_launch(void* const* d_in, const int* in_sizes, int n_in,
                              void* d_out, int out_size, void* d_ws, size_t ws_size,
                              hipStream_t stream)
{
  const float* hidden = (const float*)d_in[0];
  const float* rpe    = (const float*)d_in[1];
  const float* Wq = (const float*)d_in[2];
  const float* bq = (const float*)d_in[3];
  const float* Wk = (const float*)d_in[4];
  const float* bk = (const float*)d_in[5];
  const float* Wv = (const float*)d_in[6];
  const float* bv = (const float*)d_in[7];
  const float* Wo = (const float*)d_in[8];
  const float* bo = (const float*)d_in[9];
  const float* lns = (const float*)d_in[10];
  const float* lnb = (const float*)d_in[11];
  float* out = (float*)d_out;

  char* ws = (char*)d_ws;
  size_t off = 0;
  auto alloc = [&](size_t bytes){ void* p = ws + off; off += (bytes + 255) & ~(size_t)255; return p; };
  u16* hb      = (u16*)alloc((size_t)SEQ * HIDN * 2);         // aliased as Vt after QKV GEMM
  u16* Wt      = (u16*)alloc((size_t)3 * HIDN * HIDN * 2);    // [Wqt|Wkt|Wvt] rows
  u16* Wot     = (u16*)alloc((size_t)HIDN * HIDN * 2);
  u16* qkv     = (u16*)alloc((size_t)SEQ * 3 * HIDN * 2);
  u16* ctxb    = (u16*)alloc((size_t)SEQ * HIDN * 2);
  float* bcat  = (float*)alloc(3072 * 4);
  float* poskf = (float*)alloc(256 * 64 * 4);
  float* posq0 = (float*)alloc(64 * 4);
  float* brow  = (float*)alloc(512 * 4);
  float* biasd = (float*)alloc(1024 * 4);
  u16* Vt = hb;
  (void)ws_size; (void)in_sizes; (void)n_in; (void)out_size;

  k_f32_to_bf16<<<SEQ * HIDN / 1024, 256, 0, stream>>>(hidden, hb, SEQ * HIDN);
  dim3 tg(32, 32);
  k_transpose_bf16<<<tg, 256, 0, stream>>>(Wq, Wt);
  k_transpose_bf16<<<tg, 256, 0, stream>>>(Wk, Wt + (size_t)HIDN * HIDN);
  k_transpose_bf16<<<tg, 256, 0, stream>>>(Wv, Wt + (size_t)2 * HIDN * HIDN);
  k_transpose_bf16<<<tg, 256, 0, stream>>>(Wo, Wot);
  k_bcat<<<12, 256, 0, stream>>>(bq, bk, bv, bcat);

  dim3 gq(3 * HIDN / 128, SEQ / 128);
  k_gemm<<<gq, 256, 0, stream>>>(hb, Wt, bcat, qkv, SEQ, 3 * HIDN, HIDN, 0);

  k_vtrans<<<dim3(SEQ / 32, HIDN / 32), 256, 0, stream>>>(qkv, Vt);

  k_pos_proj<<<257, 256, 0, stream>>>(rpe, Wq, bq, Wk, bk, poskf, posq0);
  k_bias_row<<<2, 256, 0, stream>>>(qkv, poskf, posq0, brow);
  k_biasd<<<4, 256, 0, stream>>>(brow, biasd);

  k_attn<<<NBLK * NHEAD * 8, 256, 0, stream>>>(qkv, Vt, biasd, ctxb);

  dim3 go(HIDN / 128, SEQ / 128);
  k_gemm<<<go, 256, 0, stream>>>(ctxb, Wot, bo, out, SEQ, HIDN, HIDN, 1);
  k_ln<<<SEQ, 256, 0, stream>>>(out, hidden, lns, lnb, out);
}

// Round 4
// 172.726 us; speedup vs baseline: 2.0847x; 1.1154x over previous
//
#include <hip/hip_runtime.h>
#include <stdint.h>

typedef unsigned short u16;
typedef __bf16 bf16_t;
typedef bf16_t v8bf __attribute__((ext_vector_type(8)));
typedef float v4f __attribute__((ext_vector_type(4)));

#define SEQ   4096
#define HIDN  1024
#define NHEAD 16
#define HDIM  64
#define BLK   256
#define NBLK  16

#define GLOAD_LDS16(g, l) __builtin_amdgcn_global_load_lds( \
  (const __attribute__((address_space(1))) unsigned*)(g), \
  (__attribute__((address_space(3))) unsigned*)(l), 16, 0, 0)

__device__ __forceinline__ u16 f2bf(float f){
  union { float f; unsigned u; } v; v.f = f;
  unsigned r = (v.u + 0x7fffu + ((v.u >> 16) & 1u)) >> 16;   // RNE
  return (u16)r;
}
__device__ __forceinline__ float bf2f(u16 h){
  union { unsigned u; float f; } v; v.u = ((unsigned)h) << 16;
  return v.f;
}

// ---------------- fused prep: W transposes + hidden convert + bcat + pos_proj ----------------
// blocks [0,4096): W transpose tiles (w = b>>10; 32x32 tile)
// blocks [4096,4608): hidden f32->bf16 (8192 elems each)
// block  4608: bias concat
// blocks [4609,4866): pos_proj (257 blocks)
__global__ __launch_bounds__(256) void k_prep(const float* __restrict__ hidden, u16* __restrict__ hb,
    const float* __restrict__ Wq, const float* __restrict__ Wk,
    const float* __restrict__ Wv, const float* __restrict__ Wo, u16* __restrict__ Wt,
    const float* __restrict__ bq, const float* __restrict__ bk, const float* __restrict__ bv,
    float* __restrict__ bcat,
    const float* __restrict__ rpe, float* __restrict__ posk, float* __restrict__ posq0)
{
  __shared__ float t[32][33];
  __shared__ float red[4][64];
  int b = blockIdx.x, tid = threadIdx.x;
  if (b < 4096){
    int w = b >> 10, tile = b & 1023;
    int k0 = (tile & 31) * 32, n0 = (tile >> 5) * 32;
    const float* W = (w == 0) ? Wq : (w == 1) ? Wk : (w == 2) ? Wv : Wo;
    u16* outp = Wt + (size_t)w * 1024 * 1024;
    int x = tid & 31, y = tid >> 5;
    #pragma unroll
    for (int yy = 0; yy < 32; yy += 8) t[y + yy][x] = W[(size_t)(k0 + y + yy) * 1024 + n0 + x];
    __syncthreads();
    #pragma unroll
    for (int yy = 0; yy < 32; yy += 8) outp[(size_t)(n0 + y + yy) * 1024 + k0 + x] = f2bf(t[x][y + yy]);
  } else if (b < 4608){
    int base = (b - 4096) * 8192;
    #pragma unroll
    for (int j = 0; j < 8; j++){
      int i = base + j * 1024 + tid * 4;
      float4 f = *(const float4*)&hidden[i];
      unsigned u0 = (unsigned)f2bf(f.x) | ((unsigned)f2bf(f.y) << 16);
      unsigned u1 = (unsigned)f2bf(f.z) | ((unsigned)f2bf(f.w) << 16);
      uint2 p; p.x = u0; p.y = u1;
      *(uint2*)&hb[i] = p;
    }
  } else if (b == 4608){
    #pragma unroll
    for (int j = 0; j < 12; j++){
      int i = j * 256 + tid;
      const float* src = i < 1024 ? bq : (i < 2048 ? bk : bv);
      bcat[i] = src[i & 1023];
    }
  } else {
    int pb = b - 4609;   // [0,257)
    int d = tid & 63, part = tid >> 6;
    const float* W  = (pb < 256) ? Wk : Wq;
    const float* rv = (pb < 256) ? &rpe[(size_t)pb * 1024] : rpe;
    float s = 0.f;
    for (int k = part * 256; k < part * 256 + 256; k++) s += rv[k] * W[(size_t)k * 1024 + d];
    red[part][d] = s;
    __syncthreads();
    if (part == 0){
      s = red[0][d] + red[1][d] + red[2][d] + red[3][d];
      if (pb < 256) posk[pb * 64 + d] = s + bk[d];
      else          posq0[d] = s + bq[d];
    }
  }
}

// ---------------- QKV GEMM (m97 structure): qk[S][2048] = Q|K ; Vt[c][s] for V ----------------
__global__ __launch_bounds__(256) void k_gemm_qkv(const u16* __restrict__ A, const u16* __restrict__ Bt,
                                                  const float* __restrict__ bias,
                                                  u16* __restrict__ qk, u16* __restrict__ Vt)
{
  __shared__ alignas(16) u16 As[128 * 32];
  __shared__ alignas(16) u16 Bs[128 * 32];
  int tid = threadIdx.x, lane = tid & 63, wid = tid >> 6;
  int wr = wid >> 1, wc = wid & 1;
  int m0 = blockIdx.y * 128, n0 = blockIdx.x * 128;
  const int K = 1024;

  v4f acc[4][4];
  #pragma unroll
  for (int m = 0; m < 4; m++)
    #pragma unroll
    for (int n = 0; n < 4; n++) acc[m][n] = (v4f){0.f, 0.f, 0.f, 0.f};

  int r = lane & 15, g = lane >> 4;
  int ob0 = wid * 2048;

  for (int kt = 0; kt < K; kt += 32){
    #pragma unroll
    for (int t = 0; t < 2; ++t){
      int ob = ob0 + t * 1024;
      int o  = ob + lane * 16;
      int row = o >> 6, col = (o & 63) >> 1;
      GLOAD_LDS16(&A [(size_t)(m0 + row) * K + kt + col], As + (ob >> 1));
      GLOAD_LDS16(&Bt[(size_t)(n0 + row) * K + kt + col], Bs + (ob >> 1));
    }
    __syncthreads();
    v8bf a[4], bb[4];
    #pragma unroll
    for (int m = 0; m < 4; m++) a[m] = *(const v8bf*)&As[(wr * 64 + m * 16 + r) * 32 + g * 8];
    #pragma unroll
    for (int n = 0; n < 4; n++) bb[n] = *(const v8bf*)&Bs[(wc * 64 + n * 16 + r) * 32 + g * 8];
    #pragma unroll
    for (int m = 0; m < 4; m++)
      #pragma unroll
      for (int n = 0; n < 4; n++)
        acc[m][n] = __builtin_amdgcn_mfma_f32_16x16x32_bf16(a[m], bb[n], acc[m][n], 0, 0, 0);
    __syncthreads();
  }

  #pragma unroll
  for (int m = 0; m < 4; m++)
    #pragma unroll
    for (int n = 0; n < 4; n++){
      int col = n0 + wc * 64 + n * 16 + r;
      float bv = bias[col];
      #pragma unroll
      for (int i = 0; i < 4; i++){
        int row = m0 + wr * 64 + m * 16 + g * 4 + i;
        u16 h = f2bf(acc[m][n][i] + bv);
        if (col < 2048) qk[(size_t)row * 2048 + col] = h;
        else            Vt[(size_t)(col - 2048) * 4096 + row] = h;   // V stored transposed
      }
    }
}

// ---------------- out GEMM + residual: out[S][1024] = ctx @ Wo^T + bo + hidden ----------------
__global__ __launch_bounds__(256) void k_gemm_out(const u16* __restrict__ A, const u16* __restrict__ Bt,
                                                  const float* __restrict__ bias,
                                                  const float* __restrict__ resid, float* __restrict__ Cout)
{
  __shared__ alignas(16) u16 As[128 * 32];
  __shared__ alignas(16) u16 Bs[128 * 32];
  int tid = threadIdx.x, lane = tid & 63, wid = tid >> 6;
  int wr = wid >> 1, wc = wid & 1;
  int m0 = blockIdx.y * 128, n0 = blockIdx.x * 128;
  const int K = 1024;

  v4f acc[4][4];
  #pragma unroll
  for (int m = 0; m < 4; m++)
    #pragma unroll
    for (int n = 0; n < 4; n++) acc[m][n] = (v4f){0.f, 0.f, 0.f, 0.f};

  int r = lane & 15, g = lane >> 4;
  int ob0 = wid * 2048;

  for (int kt = 0; kt < K; kt += 32){
    #pragma unroll
    for (int t = 0; t < 2; ++t){
      int ob = ob0 + t * 1024;
      int o  = ob + lane * 16;
      int row = o >> 6, col = (o & 63) >> 1;
      GLOAD_LDS16(&A [(size_t)(m0 + row) * K + kt + col], As + (ob >> 1));
      GLOAD_LDS16(&Bt[(size_t)(n0 + row) * K + kt + col], Bs + (ob >> 1));
    }
    __syncthreads();
    v8bf a[4], bb[4];
    #pragma unroll
    for (int m = 0; m < 4; m++) a[m] = *(const v8bf*)&As[(wr * 64 + m * 16 + r) * 32 + g * 8];
    #pragma unroll
    for (int n = 0; n < 4; n++) bb[n] = *(const v8bf*)&Bs[(wc * 64 + n * 16 + r) * 32 + g * 8];
    #pragma unroll
    for (int m = 0; m < 4; m++)
      #pragma unroll
      for (int n = 0; n < 4; n++)
        acc[m][n] = __builtin_amdgcn_mfma_f32_16x16x32_bf16(a[m], bb[n], acc[m][n], 0, 0, 0);
    __syncthreads();
  }

  #pragma unroll
  for (int m = 0; m < 4; m++)
    #pragma unroll
    for (int n = 0; n < 4; n++){
      int col = n0 + wc * 64 + n * 16 + r;
      float bv = bias[col];
      #pragma unroll
      for (int i = 0; i < 4; i++){
        int row = m0 + wr * 64 + m * 16 + g * 4 + i;
        Cout[(size_t)row * 1024 + col] = acc[m][n][i] + bv + resid[(size_t)row * 1024 + col];
      }
    }
}

// ---------------- bias kernel (one block): brow[512] then biasd[1024] ----------------
__global__ __launch_bounds__(256) void k_bias(const u16* __restrict__ qk,
                                              const float* __restrict__ posk, const float* __restrict__ posq0,
                                              float* __restrict__ biasd)
{
  __shared__ float brow[512];
  int tid = threadIdx.x;
  brow[tid] = 0.f;
  {
    int u = tid;
    float c2p = 0.f, p2c = 0.f;
    for (int d = 0; d < 64; d++){
      c2p += bf2f(qk[d]) * posk[u * 64 + d];                  // q row0 head0
      p2c += posq0[d] * bf2f(qk[(size_t)u * 2048 + 1024 + d]); // k row u head0
    }
    brow[256 + u] = c2p + p2c;
  }
  __syncthreads();
  #pragma unroll
  for (int j = 0; j < 4; j++){
    int t = tid + j * 256;   // [0,1024)
    int rel = t - 767;
    int bucket;
    bool in_exact = (rel < 128) && (rel > -128);
    int abs_pos = in_exact ? 127 : (rel < 0 ? -rel : rel);
    if (abs_pos <= 128) bucket = rel;
    else {
      float xx = logf((float)abs_pos * (1.0f / 128.0f)) / logf(255.0f / 128.0f);
      float lp = ceilf(xx * 127.0f) + 128.0f;
      int sgn = (rel > 0) ? 1 : ((rel < 0) ? -1 : 0);
      bucket = (int)lp * sgn;
    }
    int idx = bucket + 256;
    idx = idx < 0 ? 0 : (idx > 511 ? 511 : idx);
    biasd[t] = brow[idx];
  }
}

// ---------------- fused local attention: WG = (n, h, qtile of 32 rows) ----------------
// Ss stores use XOR column-block swizzle keyed on row-quad -> conflict-free ds_write.
__global__ __launch_bounds__(256) void k_attn(const u16* __restrict__ qk, const u16* __restrict__ Vt,
                                              const float* __restrict__ biasd, u16* __restrict__ ctxg)
{
  __shared__ alignas(16) u16 Qs[32 * 72];
  __shared__ alignas(16) u16 KVs[128 * 72];          // K chunk [128][72] / Vt chunk [64][136]
  __shared__ alignas(16) u16 Ss[32 * 776];           // swizzled exp-scores, bf16
  __shared__ float invsum[32];
  __shared__ float bias_s[1024];

  int b = blockIdx.x;
  int qt = b & 7, h = (b >> 3) & 15, n = b >> 7;
  int tid = threadIdx.x, lane = tid & 63, wid = tid >> 6;
  int q0 = n * 256 + qt * 32;
  int qb0 = qt * 32;
  int g0 = (n - 1) * 256;
  const float inv_scale = 0.07216878364870323f;  // 1/sqrt(192)

  { // stage Q [32][64] + bias table
    int row = tid >> 3, seg = tid & 7;
    *(uint4*)&Qs[row * 72 + seg * 8] =
      *(const uint4*)&qk[(size_t)(q0 + row) * 2048 + h * 64 + seg * 8];
    *(float4*)&bias_s[tid * 4] = *(const float4*)&biasd[tid * 4];
  }
  __syncthreads();

  int r = lane & 15, g = lane >> 4;
  int qf = wid >> 1;                 // q fragment (16 rows)
  int kh = wid & 1;                  // k half (64 cols) in QK
  int dh = wid & 1;                  // d half (32 cols) in PV

  // ---- phase 1: scores -> Ss (swizzled) ----
  for (int c = 0; c < 6; ++c){
    int cb = g0 + c * 128;
    bool oob = (cb < 0) || (cb >= SEQ);
    if (!oob){
      #pragma unroll
      for (int it = 0; it < 2; ++it){   // stage K chunk [128][64]
        int row = it * 64 + (tid >> 2), seg = tid & 3;
        const u16* src = &qk[(size_t)(cb + row) * 2048 + 1024 + h * 64 + seg * 16];
        *(uint4*)&KVs[row * 72 + seg * 16]     = *(const uint4*)&src[0];
        *(uint4*)&KVs[row * 72 + seg * 16 + 8] = *(const uint4*)&src[8];
      }
    }
    __syncthreads();
    v4f sacc[4];
    #pragma unroll
    for (int nn = 0; nn < 4; nn++) sacc[nn] = (v4f){0.f,0.f,0.f,0.f};
    if (!oob){
      #pragma unroll
      for (int ks = 0; ks < 2; ++ks){
        v8bf a = *(const v8bf*)&Qs[(qf * 16 + r) * 72 + ks * 32 + g * 8];
        #pragma unroll
        for (int nn = 0; nn < 4; nn++){
          v8bf bb = *(const v8bf*)&KVs[(kh * 64 + nn * 16 + r) * 72 + ks * 32 + g * 8];
          sacc[nn] = __builtin_amdgcn_mfma_f32_16x16x32_bf16(a, bb, sacc[nn], 0, 0, 0);
        }
      }
    }
    #pragma unroll
    for (int nn = 0; nn < 4; nn++){
      int kcol = c * 128 + kh * 64 + nn * 16 + r;       // logical column
      int scol = kcol ^ (g << 4);                        // swizzled column
      #pragma unroll
      for (int i = 0; i < 4; i++){
        int qrow = qf * 16 + g * 4 + i;
        float sc = (sacc[nn][i] + bias_s[qb0 + qrow - kcol + 767]) * inv_scale;
        Ss[qrow * 776 + scol] = f2bf(sc);
      }
    }
    __syncthreads();
  }

  // ---- phase 2: vectorized softmax (order-independent over swizzled data) ----
  {
    int row = tid >> 3, sub = tid & 7;
    u16* srow = &Ss[row * 776 + sub * 96];
    float mx = -3.0e38f;
    #pragma unroll
    for (int ii = 0; ii < 12; ii++){
      uint4 pk = *(const uint4*)&srow[ii * 8];
      const unsigned* w = (const unsigned*)&pk;
      #pragma unroll
      for (int j = 0; j < 4; j++){
        mx = fmaxf(mx, bf2f((u16)(w[j] & 0xffff)));
        mx = fmaxf(mx, bf2f((u16)(w[j] >> 16)));
      }
    }
    mx = fmaxf(mx, __shfl_xor(mx, 1));
    mx = fmaxf(mx, __shfl_xor(mx, 2));
    mx = fmaxf(mx, __shfl_xor(mx, 4));
    float sm = 0.f;
    #pragma unroll
    for (int ii = 0; ii < 12; ii++){
      uint4 pk = *(const uint4*)&srow[ii * 8];
      unsigned* w = (unsigned*)&pk;
      #pragma unroll
      for (int j = 0; j < 4; j++){
        float e0 = __expf(bf2f((u16)(w[j] & 0xffff)) - mx);
        float e1 = __expf(bf2f((u16)(w[j] >> 16)) - mx);
        sm += e0 + e1;
        w[j] = (unsigned)f2bf(e0) | ((unsigned)f2bf(e1) << 16);
      }
      *(uint4*)&srow[ii * 8] = pk;
    }
    sm += __shfl_xor(sm, 1);
    sm += __shfl_xor(sm, 2);
    sm += __shfl_xor(sm, 4);
    if (sub == 0) invsum[row] = 1.0f / sm;
  }
  __syncthreads();

  // ---- phase 3: PV (reads apply the same row-keyed swizzle) ----
  v4f pacc[2];
  pacc[0] = (v4f){0.f,0.f,0.f,0.f};
  pacc[1] = (v4f){0.f,0.f,0.f,0.f};
  int swr = ((r >> 2) & 3) << 4;     // swizzle for row qf*16+r
  for (int c = 0; c < 6; ++c){
    int cb = g0 + c * 128;
    bool oob = (cb < 0) || (cb >= SEQ);
    if (!oob){
      int d = tid >> 2, seg = tid & 3;
      const u16* src = &Vt[(size_t)(h * 64 + d) * 4096 + cb];
      #pragma unroll
      for (int ii = 0; ii < 4; ii++)
        *(uint4*)&KVs[d * 136 + (ii * 4 + seg) * 8] = *(const uint4*)&src[(ii * 4 + seg) * 8];
    }
    __syncthreads();
    if (!oob){
      #pragma unroll
      for (int ks = 0; ks < 4; ++ks){
        v8bf a = *(const v8bf*)&Ss[(qf * 16 + r) * 776 + ((c * 128 + ks * 32 + g * 8) ^ swr)];
        #pragma unroll
        for (int nn = 0; nn < 2; nn++){
          v8bf bb = *(const v8bf*)&KVs[(dh * 32 + nn * 16 + r) * 136 + ks * 32 + g * 8];
          pacc[nn] = __builtin_amdgcn_mfma_f32_16x16x32_bf16(a, bb, pacc[nn], 0, 0, 0);
        }
      }
    }
    __syncthreads();
  }
  #pragma unroll
  for (int nn = 0; nn < 2; nn++){
    int d = dh * 32 + nn * 16 + r;
    #pragma unroll
    for (int i = 0; i < 4; i++){
      int qrow = qf * 16 + g * 4 + i;
      float val = pacc[nn][i] * invsum[qrow];
      ctxg[(size_t)(q0 + qrow) * 1024 + h * 64 + d] = f2bf(val);
    }
  }
}

// ---------------- LayerNorm in place (residual already folded into out) ----------------
__global__ __launch_bounds__(256) void k_ln(float* __restrict__ out,
                                            const float* __restrict__ gamma, const float* __restrict__ beta)
{
  __shared__ float red[8];
  int row = blockIdx.x, tid = threadIdx.x;
  int lane = tid & 63, wid = tid >> 6;
  size_t base = (size_t)row * 1024 + tid * 4;
  float4 xv = *(const float4*)&out[base];
  float v0 = xv.x, v1 = xv.y, v2 = xv.z, v3 = xv.w;
  float s = v0 + v1 + v2 + v3;
  float q = v0 * v0 + v1 * v1 + v2 * v2 + v3 * v3;
  #pragma unroll
  for (int o = 32; o; o >>= 1){ s += __shfl_down(s, o); q += __shfl_down(q, o); }
  if (lane == 0){ red[wid] = s; red[4 + wid] = q; }
  __syncthreads();
  float ts = red[0] + red[1] + red[2] + red[3];
  float tq = red[4] + red[5] + red[6] + red[7];
  float mu = ts * (1.0f / 1024.0f);
  float var = tq * (1.0f / 1024.0f) - mu * mu;
  float rstd = rsqrtf(var + 1e-7f);
  int c = tid * 4;
  out[base + 0] = (v0 - mu) * rstd * gamma[c + 0] + beta[c + 0];
  out[base + 1] = (v1 - mu) * rstd * gamma[c + 1] + beta[c + 1];
  out[base + 2] = (v2 - mu) * rstd * gamma[c + 2] + beta[c + 2];
  out[base + 3] = (v3 - mu) * rstd * gamma[c + 3] + beta[c + 3];
}

extern "C" void kernel_launch(void* const* d_in, const int* in_sizes, int n_in,
                              void* d_out, int out_size, void* d_ws, size_t ws_size,
                              hipStream_t stream)
{
  const float* hidden = (const float*)d_in[0];
  const float* rpe    = (const float*)d_in[1];
  const float* Wq = (const float*)d_in[2];
  const float* bq = (const float*)d_in[3];
  const float* Wk = (const float*)d_in[4];
  const float* bk = (const float*)d_in[5];
  const float* Wv = (const float*)d_in[6];
  const float* bv = (const float*)d_in[7];
  const float* Wo = (const float*)d_in[8];
  const float* bo = (const float*)d_in[9];
  const float* lns = (const float*)d_in[10];
  const float* lnb = (const float*)d_in[11];
  float* out = (float*)d_out;

  char* ws = (char*)d_ws;
  size_t off = 0;
  auto alloc = [&](size_t bytes){ void* p = ws + off; off += (bytes + 255) & ~(size_t)255; return p; };
  u16* hb      = (u16*)alloc((size_t)SEQ * HIDN * 2);
  u16* Wt      = (u16*)alloc((size_t)4 * HIDN * HIDN * 2);    // [Wqt|Wkt|Wvt|Wot]
  u16* qk      = (u16*)alloc((size_t)SEQ * 2048 * 2);
  u16* Vt      = (u16*)alloc((size_t)HIDN * SEQ * 2);
  u16* ctxb    = (u16*)alloc((size_t)SEQ * HIDN * 2);
  float* bcat  = (float*)alloc(3072 * 4);
  float* poskf = (float*)alloc(256 * 64 * 4);
  float* posq0 = (float*)alloc(64 * 4);
  float* biasd = (float*)alloc(1024 * 4);
  (void)ws_size; (void)in_sizes; (void)n_in; (void)out_size;

  k_prep<<<4866, 256, 0, stream>>>(hidden, hb, Wq, Wk, Wv, Wo, Wt,
                                   bq, bk, bv, bcat, rpe, poskf, posq0);

  k_gemm_qkv<<<dim3(24, 32), 256, 0, stream>>>(hb, Wt, bcat, qk, Vt);

  k_bias<<<1, 256, 0, stream>>>(qk, poskf, posq0, biasd);

  k_attn<<<NBLK * NHEAD * 8, 256, 0, stream>>>(qk, Vt, biasd, ctxb);

  k_gemm_out<<<dim3(8, 32), 256, 0, stream>>>(ctxb, Wt + (size_t)3 * HIDN * HIDN, bo, hidden, out);

  k_ln<<<SEQ, 256, 0, stream>>>(out, lns, lnb);
}